// Round 1
// baseline (346.756 us; speedup 1.0000x reference)
//
#include <hip/hip_runtime.h>
#include <math.h>

// Pruned-cone evaluation: only the query asset's 2-hop GATv2 dependency cone
// is computed. Capacities are ~40x the expected (random-graph) cone sizes.
#define FAMAX 512    // frontier assets (expected ~10)
#define FCMAX 256    // frontier creators (expected ~2)
#define FLMAX 256    // frontier licensees (expected ~3)
#define N1MAX 4096   // layer-1 edges into frontier (expected ~130)
#define N2MAX 512    // layer-2 edges into query (expected ~9)

struct Inputs {
  const float *x_asset, *x_creator, *x_licensee;
  const float *Wp_a,*bp_a,*Wp_c,*bp_c,*Wp_l,*bp_l;
  const float *Wl1,*bl1,*Wr1,*br1,*We1,*att1,*bias1;
  const float *Wl2,*bl2,*Wr2,*br2,*We2,*att2,*bias2;
  const float *Wc1,*bc1,*Wc2,*bc2;
};

struct Edges {
  const int *cb_s,*cb_d;  const float* ea_cb;  int Ecb;
  const int *lt_s,*lt_d;  const float* ea_lt;  int Elt;
  const int *sim_s,*sim_d;const float* ea_sim; int Esim;
  const int *fw_s,*fw_d;  const float* ea_fw;  int Efw;
  const int *rcb_s,*rcb_d;const float* ea_rcb; int Ercb;
  const int *rlt_s,*rlt_d;const float* ea_rlt; int Erlt;
};

struct WSP {
  int* cnt;       // [0]=n_l2e [1]=na [2]=nc [3]=nl [4]=n_l1e
  int* flagA; int* flagC; int* flagL;   // 0=unused, 1=marked, k+2=slot k
  int* fa; int* fc; int* fl;            // frontier node ids
  int* l2rel; int* l2src; float* l2ea;
  int* l1rel; int* l1src; int* l1dslot; float* l1ea;
  float* xr1a;   // [FAMAX][4][256]  (rels 2..5)
  float* xr1c;   // [FCMAX][256]     (rel 0)
  float* xr1l;   // [FLMAX][256]     (rel 1)
  float* xl1e;   // [N1MAX][256]
  float* logit1; // [N1MAX][2]
  float* x1a;    // [FAMAX][128]
  float* x1c;    // [FCMAX][128]
  float* x1l;    // [FLMAX][128]
  float* xr2q;   // [4][128]
  float* xl2e;   // [N2MAX][128]
  float* logit2; // [N2MAX]
};

__device__ __forceinline__ float leaky(float x){ return x > 0.f ? x : 0.2f*x; }

// Project raw node features -> 128-d (into LDS h0). type: 0=Asset,1=Creator,2=Licensee
__device__ void proj_node(int type, int node, const Inputs& in, float* h0){
  int t = threadIdx.x;
  if (t < 128) {
    float acc;
    if (type == 0) {
      acc = in.bp_a[t];
      const float* xr = in.x_asset + (long long)node*512;
      for (int k=0;k<512;k++) acc = fmaf(xr[k], in.Wp_a[k*128+t], acc);
    } else if (type == 1) {
      acc = in.bp_c[t] + in.x_creator[node*2]*in.Wp_c[t] + in.x_creator[node*2+1]*in.Wp_c[128+t];
    } else {
      acc = in.bp_l[t] + in.x_licensee[node]*in.Wp_l[t];
    }
    h0[t] = acc;
  }
  __syncthreads();
}

// K1: scan Asset-targeting relations for dst == q; build L2 edge list + mark frontier.
__global__ void k1_scan_l2(Edges eg, const int* qptr, WSP w){
  int q = qptr[0];
  if (blockIdx.x==0 && threadIdx.x==0) w.flagA[q] = 1;
  int total = eg.Esim + eg.Efw + eg.Ercb + eg.Erlt;
  for (int i = blockIdx.x*blockDim.x + threadIdx.x; i < total; i += gridDim.x*blockDim.x){
    int j = i, rel; const int *sp,*dp; const float* ep;
    if (j < eg.Esim){ rel=2; sp=eg.sim_s; dp=eg.sim_d; ep=eg.ea_sim; }
    else { j -= eg.Esim;
      if (j < eg.Efw){ rel=3; sp=eg.fw_s; dp=eg.fw_d; ep=eg.ea_fw; }
      else { j -= eg.Efw;
        if (j < eg.Ercb){ rel=4; sp=eg.rcb_s; dp=eg.rcb_d; ep=eg.ea_rcb; }
        else { j -= eg.Ercb; rel=5; sp=eg.rlt_s; dp=eg.rlt_d; ep=eg.ea_rlt; }
      }
    }
    if (dp[j] == q){
      int src = sp[j];
      int k = atomicAdd(&w.cnt[0], 1);
      if (k < N2MAX){ w.l2rel[k]=rel; w.l2src[k]=src; w.l2ea[k]=ep[j]; }
      if (rel <= 3) w.flagA[src] = 1;
      else if (rel == 4) w.flagC[src] = 1;
      else w.flagL[src] = 1;
    }
  }
}

// K2: compact flags -> slot ids + frontier lists
__global__ void k2_compact(WSP w){
  int i = blockIdx.x*blockDim.x + threadIdx.x;
  if (i < 50000){
    if (w.flagA[i] == 1){ int k = atomicAdd(&w.cnt[1],1);
      if (k < FAMAX){ w.flagA[i]=k+2; w.fa[k]=i; } else w.flagA[i]=0; }
  } else if (i < 60000){ int n=i-50000;
    if (w.flagC[n] == 1){ int k = atomicAdd(&w.cnt[2],1);
      if (k < FCMAX){ w.flagC[n]=k+2; w.fc[k]=n; } else w.flagC[n]=0; }
  } else if (i < 70000){ int n=i-60000;
    if (w.flagL[n] == 1){ int k = atomicAdd(&w.cnt[3],1);
      if (k < FLMAX){ w.flagL[n]=k+2; w.fl[k]=n; } else w.flagL[n]=0; }
  }
}

// K3: scan all 6 relations for dst in frontier -> L1 edge list
__global__ void k3_scan_l1(Edges eg, WSP w){
  int total = eg.Ecb+eg.Elt+eg.Esim+eg.Efw+eg.Ercb+eg.Erlt;
  for (int i = blockIdx.x*blockDim.x + threadIdx.x; i < total; i += gridDim.x*blockDim.x){
    int j = i, rel; const int *sp,*dp; const float* ep; const int* flag;
    if (j < eg.Ecb){ rel=0; sp=eg.cb_s; dp=eg.cb_d; ep=eg.ea_cb; flag=w.flagC; }
    else { j -= eg.Ecb;
    if (j < eg.Elt){ rel=1; sp=eg.lt_s; dp=eg.lt_d; ep=eg.ea_lt; flag=w.flagL; }
    else { j -= eg.Elt;
    if (j < eg.Esim){ rel=2; sp=eg.sim_s; dp=eg.sim_d; ep=eg.ea_sim; flag=w.flagA; }
    else { j -= eg.Esim;
    if (j < eg.Efw){ rel=3; sp=eg.fw_s; dp=eg.fw_d; ep=eg.ea_fw; flag=w.flagA; }
    else { j -= eg.Efw;
    if (j < eg.Ercb){ rel=4; sp=eg.rcb_s; dp=eg.rcb_d; ep=eg.ea_rcb; flag=w.flagA; }
    else { j -= eg.Ercb; rel=5; sp=eg.rlt_s; dp=eg.rlt_d; ep=eg.ea_rlt; flag=w.flagA; }}}}}
    int f = flag[dp[j]];
    if (f >= 2){
      int k = atomicAdd(&w.cnt[4], 1);
      if (k < N1MAX){ w.l1rel[k]=rel; w.l1src[k]=sp[j]; w.l1dslot[k]=f-2; w.l1ea[k]=ep[j]; }
    }
  }
}

// K4: xr1 for each frontier node x relevant relation
__global__ void k4_xr1(Inputs in, WSP w){
  __shared__ float h0[128];
  int b = blockIdx.x;
  int na = w.cnt[1] < FAMAX ? w.cnt[1] : FAMAX;
  int nc = w.cnt[2] < FCMAX ? w.cnt[2] : FCMAX;
  int nl = w.cnt[3] < FLMAX ? w.cnt[3] : FLMAX;
  int rel; float* dst;
  if (b < FAMAX*4){
    int slot = b>>2, ridx = b&3;
    if (slot >= na) return;
    rel = 2 + ridx;
    proj_node(0, w.fa[slot], in, h0);
    dst = w.xr1a + ((size_t)slot*4 + ridx)*256;
  } else if (b < FAMAX*4 + FCMAX){
    int slot = b - FAMAX*4;
    if (slot >= nc) return;
    rel = 0;
    proj_node(1, w.fc[slot], in, h0);
    dst = w.xr1c + (size_t)slot*256;
  } else {
    int slot = b - FAMAX*4 - FCMAX;
    if (slot >= nl) return;
    rel = 1;
    proj_node(2, w.fl[slot], in, h0);
    dst = w.xr1l + (size_t)slot*256;
  }
  int j = threadIdx.x; // 256
  float acc = in.br1[rel*256 + j];
  const float* W = in.Wr1 + (size_t)rel*128*256;
  for (int c=0;c<128;c++) acc = fmaf(h0[c], W[c*256 + j], acc);
  dst[j] = acc;
}

// K5: per L1 edge: project src, xl1, logit per head
__global__ void k5_l1edge(Inputs in, WSP w){
  __shared__ float h0[128];
  __shared__ float red[256];
  int i = blockIdx.x;
  int n = w.cnt[4] < N1MAX ? w.cnt[4] : N1MAX;
  if (i >= n) return;
  int rel = w.l1rel[i], src = w.l1src[i], dslot = w.l1dslot[i];
  float ea = w.l1ea[i];
  int stype = (rel <= 3) ? 0 : (rel == 4 ? 1 : 2);
  proj_node(stype, src, in, h0);
  int j = threadIdx.x; // 256
  float acc = in.bl1[rel*256 + j];
  const float* W = in.Wl1 + (size_t)rel*128*256;
  for (int c=0;c<128;c++) acc = fmaf(h0[c], W[c*256 + j], acc);
  w.xl1e[(size_t)i*256 + j] = acc;
  const float* xr;
  if (rel >= 2) xr = w.xr1a + ((size_t)dslot*4 + (rel-2))*256;
  else if (rel == 0) xr = w.xr1c + (size_t)dslot*256;
  else xr = w.xr1l + (size_t)dslot*256;
  float e = leaky(acc + xr[j] + ea*in.We1[rel*256 + j]);
  int h = j >> 7, c = j & 127;
  red[j] = e * in.att1[(rel*2 + h)*128 + c];
  __syncthreads();
  for (int s=64; s>0; s>>=1){ if (c < s) red[j] += red[j+s]; __syncthreads(); }
  if (c == 0) w.logit1[i*2 + h] = red[j];
}

// K6: per frontier node: segment softmax per relation, aggregate, relu -> x1
__global__ void k6_agg(Inputs in, WSP w){
  int b = blockIdx.x;
  int na = w.cnt[1] < FAMAX ? w.cnt[1] : FAMAX;
  int nc = w.cnt[2] < FCMAX ? w.cnt[2] : FCMAX;
  int nl = w.cnt[3] < FLMAX ? w.cnt[3] : FLMAX;
  int type, slot;
  if (b < FAMAX){ slot = b; if (slot >= na) return; type = 0; }
  else if (b < FAMAX+FCMAX){ slot = b-FAMAX; if (slot >= nc) return; type = 1; }
  else { slot = b-FAMAX-FCMAX; if (slot >= nl) return; type = 2; }
  int n1 = w.cnt[4] < N1MAX ? w.cnt[4] : N1MAX;
  int j = threadIdx.x; // 128
  float out = 0.f;
  int r0, r1;
  if (type == 0){ r0=2; r1=5; } else if (type == 1){ r0=0; r1=0; } else { r0=1; r1=1; }
  for (int r=r0; r<=r1; r++){
    out += in.bias1[r*128 + j];
    float m0 = -INFINITY, m1 = -INFINITY;
    for (int i=0;i<n1;i++){
      if (w.l1rel[i]==r && w.l1dslot[i]==slot){
        m0 = fmaxf(m0, w.logit1[i*2]);
        m1 = fmaxf(m1, w.logit1[i*2+1]);
      }
    }
    if (m0 == -INFINITY) continue;
    float d0=0.f, d1=0.f, a0=0.f, a1=0.f;
    for (int i=0;i<n1;i++){
      if (w.l1rel[i]==r && w.l1dslot[i]==slot){
        float e0 = expf(w.logit1[i*2]   - m0);
        float e1 = expf(w.logit1[i*2+1] - m1);
        d0 += e0; d1 += e1;
        a0 = fmaf(e0, w.xl1e[(size_t)i*256 + j], a0);
        a1 = fmaf(e1, w.xl1e[(size_t)i*256 + 128 + j], a1);
      }
    }
    out += 0.5f*(a0/(d0+1e-16f) + a1/(d1+1e-16f));
  }
  float v = fmaxf(out, 0.f);
  if (type == 0) w.x1a[slot*128 + j] = v;
  else if (type == 1) w.x1c[slot*128 + j] = v;
  else w.x1l[slot*128 + j] = v;
}

// K7: xr2 for the query node, rels 2..5
__global__ void k7_xr2(Inputs in, WSP w, const int* qptr){
  int q = qptr[0];
  int qslot = w.flagA[q] - 2;
  const float* xq = w.x1a + (size_t)qslot*128;
  int j = threadIdx.x; // 128
  for (int ridx=0; ridx<4; ridx++){
    int r = 2 + ridx;
    float acc = in.br2[r*128 + j];
    const float* W = in.Wr2 + (size_t)r*128*128;
    for (int c=0;c<128;c++) acc = fmaf(xq[c], W[c*128 + j], acc);
    w.xr2q[ridx*128 + j] = acc;
  }
}

// K8: per L2 edge: xl2 + logit (H=1)
__global__ void k8_l2edge(Inputs in, WSP w){
  __shared__ float red[128];
  int i = blockIdx.x;
  int n2 = w.cnt[0] < N2MAX ? w.cnt[0] : N2MAX;
  if (i >= n2) return;
  int rel = w.l2rel[i], src = w.l2src[i];
  float ea = w.l2ea[i];
  int f;
  const float* xbase;
  if (rel <= 3){ f = w.flagA[src]; xbase = w.x1a; }
  else if (rel == 4){ f = w.flagC[src]; xbase = w.x1c; }
  else { f = w.flagL[src]; xbase = w.x1l; }
  if (f < 2) return; // capacity overflow guard
  const float* xsrc = xbase + (size_t)(f-2)*128;
  int j = threadIdx.x; // 128
  float acc = in.bl2[rel*128 + j];
  const float* W = in.Wl2 + (size_t)rel*128*128;
  for (int c=0;c<128;c++) acc = fmaf(xsrc[c], W[c*128 + j], acc);
  w.xl2e[(size_t)i*128 + j] = acc;
  float e = leaky(acc + w.xr2q[(rel-2)*128 + j] + ea*in.We2[rel*128 + j]);
  red[j] = e * in.att2[rel*128 + j];
  __syncthreads();
  for (int s=64; s>0; s>>=1){ if (j < s) red[j] += red[j+s]; __syncthreads(); }
  if (j == 0) w.logit2[i] = red[0];
}

// K9: layer-2 softmax + aggregate + relu, then classifier head -> d_out[3]
__global__ void k9_final(Inputs in, WSP w, float* out){
  __shared__ float x2[128];
  __shared__ float t[128];
  int n2 = w.cnt[0] < N2MAX ? w.cnt[0] : N2MAX;
  int j = threadIdx.x; // 128
  float o = 0.f;
  for (int r=2; r<=5; r++){
    o += in.bias2[r*128 + j];
    float m = -INFINITY;
    for (int i=0;i<n2;i++) if (w.l2rel[i]==r) m = fmaxf(m, w.logit2[i]);
    if (m == -INFINITY) continue;
    float d = 0.f, acc = 0.f;
    for (int i=0;i<n2;i++) if (w.l2rel[i]==r){
      float e = expf(w.logit2[i] - m);
      d += e;
      acc = fmaf(e, w.xl2e[(size_t)i*128 + j], acc);
    }
    o += acc/(d + 1e-16f);
  }
  x2[j] = fmaxf(o, 0.f);
  __syncthreads();
  float acc = in.bc1[j];
  for (int c=0;c<128;c++) acc = fmaf(x2[c], in.Wc1[c*128 + j], acc);
  t[j] = fmaxf(acc, 0.f);
  __syncthreads();
  if (j < 3){
    float r = in.bc2[j];
    for (int c=0;c<128;c++) r = fmaf(t[c], in.Wc2[c*3 + j], r);
    out[j] = r;
  }
}

extern "C" void kernel_launch(void* const* d_in, const int* in_sizes, int n_in,
                              void* d_out, int out_size, void* d_ws, size_t ws_size,
                              hipStream_t stream){
  Inputs in;
  in.x_asset   = (const float*)d_in[0];
  in.x_creator = (const float*)d_in[1];
  in.x_licensee= (const float*)d_in[2];
  Edges eg;
  eg.cb_s =(const int*)d_in[3];  eg.cb_d =(const int*)d_in[4];  eg.ea_cb =(const float*)d_in[5];  eg.Ecb = in_sizes[3];
  eg.lt_s =(const int*)d_in[6];  eg.lt_d =(const int*)d_in[7];  eg.ea_lt =(const float*)d_in[8];  eg.Elt = in_sizes[6];
  eg.sim_s=(const int*)d_in[9];  eg.sim_d=(const int*)d_in[10]; eg.ea_sim=(const float*)d_in[11]; eg.Esim= in_sizes[9];
  eg.fw_s =(const int*)d_in[12]; eg.fw_d =(const int*)d_in[13]; eg.ea_fw =(const float*)d_in[14]; eg.Efw = in_sizes[12];
  eg.rcb_s=(const int*)d_in[15]; eg.rcb_d=(const int*)d_in[16]; eg.ea_rcb=(const float*)d_in[17]; eg.Ercb= in_sizes[15];
  eg.rlt_s=(const int*)d_in[18]; eg.rlt_d=(const int*)d_in[19]; eg.ea_rlt=(const float*)d_in[20]; eg.Erlt= in_sizes[18];
  in.Wp_a=(const float*)d_in[21]; in.bp_a=(const float*)d_in[22];
  in.Wp_c=(const float*)d_in[23]; in.bp_c=(const float*)d_in[24];
  in.Wp_l=(const float*)d_in[25]; in.bp_l=(const float*)d_in[26];
  in.Wl1=(const float*)d_in[27]; in.bl1=(const float*)d_in[28];
  in.Wr1=(const float*)d_in[29]; in.br1=(const float*)d_in[30];
  in.We1=(const float*)d_in[31]; in.att1=(const float*)d_in[32]; in.bias1=(const float*)d_in[33];
  in.Wl2=(const float*)d_in[34]; in.bl2=(const float*)d_in[35];
  in.Wr2=(const float*)d_in[36]; in.br2=(const float*)d_in[37];
  in.We2=(const float*)d_in[38]; in.att2=(const float*)d_in[39]; in.bias2=(const float*)d_in[40];
  in.Wc1=(const float*)d_in[41]; in.bc1=(const float*)d_in[42];
  in.Wc2=(const float*)d_in[43]; in.bc2=(const float*)d_in[44];
  const int* qptr = (const int*)d_in[45];

  char* p = (char*)d_ws;
  auto carve = [&](size_t n)->char*{ char* r = p; p += ((n + 255) & ~(size_t)255); return r; };
  WSP w;
  w.cnt    = (int*)carve(16*4);
  w.flagA  = (int*)carve(50000*4);
  w.flagC  = (int*)carve(10000*4);
  w.flagL  = (int*)carve(10000*4);
  size_t zero_bytes = (size_t)(p - (char*)d_ws);
  w.fa = (int*)carve(FAMAX*4); w.fc = (int*)carve(FCMAX*4); w.fl = (int*)carve(FLMAX*4);
  w.l2rel=(int*)carve(N2MAX*4); w.l2src=(int*)carve(N2MAX*4); w.l2ea=(float*)carve(N2MAX*4);
  w.l1rel=(int*)carve(N1MAX*4); w.l1src=(int*)carve(N1MAX*4); w.l1dslot=(int*)carve(N1MAX*4); w.l1ea=(float*)carve(N1MAX*4);
  w.xr1a=(float*)carve((size_t)FAMAX*4*256*4);
  w.xr1c=(float*)carve((size_t)FCMAX*256*4);
  w.xr1l=(float*)carve((size_t)FLMAX*256*4);
  w.xl1e=(float*)carve((size_t)N1MAX*256*4);
  w.logit1=(float*)carve((size_t)N1MAX*2*4);
  w.x1a=(float*)carve((size_t)FAMAX*128*4);
  w.x1c=(float*)carve((size_t)FCMAX*128*4);
  w.x1l=(float*)carve((size_t)FLMAX*128*4);
  w.xr2q=(float*)carve(4*128*4);
  w.xl2e=(float*)carve((size_t)N2MAX*128*4);
  w.logit2=(float*)carve(N2MAX*4);

  hipMemsetAsync(d_ws, 0, zero_bytes, stream);

  int tE2 = eg.Esim + eg.Efw + eg.Ercb + eg.Erlt;
  k1_scan_l2<<<(tE2+255)/256, 256, 0, stream>>>(eg, qptr, w);
  k2_compact<<<(70000+255)/256, 256, 0, stream>>>(w);
  int tE1 = eg.Ecb + eg.Elt + tE2;
  k3_scan_l1<<<(tE1+255)/256, 256, 0, stream>>>(eg, w);
  k4_xr1<<<FAMAX*4 + FCMAX + FLMAX, 256, 0, stream>>>(in, w);
  k5_l1edge<<<N1MAX, 256, 0, stream>>>(in, w);
  k6_agg<<<FAMAX + FCMAX + FLMAX, 128, 0, stream>>>(in, w);
  k7_xr2<<<1, 128, 0, stream>>>(in, w, qptr);
  k8_l2edge<<<N2MAX, 128, 0, stream>>>(in, w);
  k9_final<<<1, 128, 0, stream>>>(in, w, (float*)d_out);
}